// Round 3
// baseline (735.772 us; speedup 1.0000x reference)
//
#include <hip/hip_runtime.h>

#define BB 2048
#define NN 1568
#define CD 48
#define NCHUNK 98          // n-chunks of 16; 98*16 = 1568

// ---------------- pass kernel ----------------
// block = 256 threads = 32 bl (batch) x 2 h (cd-half within c) x 4 ns (n-split)
// block covers: 32 batches (bg) x 16 n (chunk g). W tile staged in LDS once.
// thread computes 24 cd values: (c in 0..2) x (d in h*8 .. h*8+8)
// PASS 0: partial[g][b][cd] = sum_n u[b,n,cd]
// PASS 1/2: partial = sum_n softmax_c(vin . u) * u
template<int PASS>
__global__ __launch_bounds__(256, 4)
void caps_pass(const float* __restrict__ x, const float* __restrict__ W,
               const float* __restrict__ vin, float* __restrict__ part)
{
    __shared__ float wlds[16 * 384];   // 24,576 B: [n-row][c*128 + d*8 + e]
    const int t  = threadIdx.x;
    const int bl = t & 31;
    const int h  = (t >> 5) & 1;
    const int ns = t >> 6;
    const int tl = t & 63;
    const int bg = blockIdx.x & 63;
    const int g  = blockIdx.x >> 6;
    const int b  = bg * 32 + bl;
    const int n0 = g * 16;

    // ---- stage W[c, n0:n0+16, :, :] -> wlds (coalesced, 6 float4 per thread)
#pragma unroll
    for (int k = 0; k < 6; ++k) {
        const int q = t + k * 256;           // float4 index 0..1535
        const int c = q >> 9;                // 512 float4 per c
        const int j = (q >> 5) & 15;         // n-row
        const int f = q & 31;                // float4 within row-c
        const float4 v = *(const float4*)(W + (((size_t)(c * NN + n0 + j)) << 7) + (f << 2));
        *(float4*)(wlds + j * 384 + c * 128 + (f << 2)) = v;
    }

    // ---- per-thread routing vector (24 of 48: cd = c*16 + h*8 + dd)
    float vv[24];
    if (PASS > 0) {
#pragma unroll
        for (int c = 0; c < 3; ++c) {
            const float4 a = __ldg((const float4*)(vin + b * CD + c * 16 + h * 8));
            const float4 q2 = __ldg((const float4*)(vin + b * CD + c * 16 + h * 8 + 4));
            vv[c*8+0]=a.x;  vv[c*8+1]=a.y;  vv[c*8+2]=a.z;  vv[c*8+3]=a.w;
            vv[c*8+4]=q2.x; vv[c*8+5]=q2.y; vv[c*8+6]=q2.z; vv[c*8+7]=q2.w;
        }
    }
    __syncthreads();

    float acc[24];
#pragma unroll
    for (int j = 0; j < 24; ++j) acc[j] = 0.f;

    // ---- main loop: this thread's 4 n
#pragma unroll
    for (int i = 0; i < 4; ++i) {
        const int nr = ns * 4 + i;
        const int n  = n0 + nr;
        const float4 x0 = __ldg((const float4*)(x + ((size_t)b * NN + n) * 8));
        const float4 x1 = __ldg((const float4*)(x + ((size_t)b * NN + n) * 8 + 4));

        float U[24];
        const float* wrow = wlds + nr * 384 + h * 64;
#pragma unroll
        for (int c = 0; c < 3; ++c) {
            const float* wc = wrow + c * 128;
#pragma unroll
            for (int p = 0; p < 4; ++p) {    // d-pair p: dd = 2p, 2p+1
                const float4 w0 = *(const float4*)(wc + 16 * p);
                const float4 w1 = *(const float4*)(wc + 16 * p + 4);
                const float4 w2 = *(const float4*)(wc + 16 * p + 8);
                const float4 w3 = *(const float4*)(wc + 16 * p + 12);
                U[c*8 + 2*p]     = w0.x*x0.x + w0.y*x0.y + w0.z*x0.z + w0.w*x0.w
                                 + w1.x*x1.x + w1.y*x1.y + w1.z*x1.z + w1.w*x1.w;
                U[c*8 + 2*p + 1] = w2.x*x0.x + w2.y*x0.y + w2.z*x0.z + w2.w*x0.w
                                 + w3.x*x1.x + w3.y*x1.y + w3.z*x1.z + w3.w*x1.w;
            }
        }

        if (PASS == 0) {
#pragma unroll
            for (int j = 0; j < 24; ++j) acc[j] += U[j];
        } else {
            float lp0 = 0.f, lp1 = 0.f, lp2 = 0.f;
#pragma unroll
            for (int d = 0; d < 8; ++d) {
                lp0 += vv[d]      * U[d];
                lp1 += vv[8 + d]  * U[8 + d];
                lp2 += vv[16 + d] * U[16 + d];
            }
            // combine the two d-halves (lane ^ 32 = other h, same bl)
            const float l0 = lp0 + __shfl_xor(lp0, 32);
            const float l1 = lp1 + __shfl_xor(lp1, 32);
            const float l2 = lp2 + __shfl_xor(lp2, 32);
            const float mx = fmaxf(l0, fmaxf(l1, l2));
            const float e0 = __expf(l0 - mx), e1 = __expf(l1 - mx), e2 = __expf(l2 - mx);
            const float inv = 1.f / (e0 + e1 + e2);
            const float c0 = e0 * inv, c1 = e1 * inv, c2 = e2 * inv;
#pragma unroll
            for (int d = 0; d < 8; ++d) {
                acc[d]      += c0 * U[d];
                acc[8 + d]  += c1 * U[8 + d];
                acc[16 + d] += c2 * U[16 + d];
            }
        }
    }

    // ---- in-block reduction over ns (reuse wlds; 3*1536 = 4608 <= 6144 floats)
    __syncthreads();
    if (ns > 0) {
        float* dst = wlds + (ns - 1) * 1536 + tl * 24;
        const float4* s = (const float4*)acc;
#pragma unroll
        for (int k = 0; k < 6; ++k) ((float4*)dst)[k] = s[k];
    }
    __syncthreads();
    if (ns == 0) {
#pragma unroll
        for (int k = 0; k < 3; ++k) {
            const float* src = wlds + k * 1536 + tl * 24;
#pragma unroll
            for (int j = 0; j < 24; ++j) acc[j] += src[j];
        }
        // store: thread's 24 cd are, per c, cd_lin = c*16 + h*8 + dd
        float* pb = part + ((size_t)g * BB + b) * CD + h * 8;
#pragma unroll
        for (int c = 0; c < 3; ++c) {
            float4 s0, s1;
            s0.x = acc[c*8+0]; s0.y = acc[c*8+1]; s0.z = acc[c*8+2]; s0.w = acc[c*8+3];
            s1.x = acc[c*8+4]; s1.y = acc[c*8+5]; s1.z = acc[c*8+6]; s1.w = acc[c*8+7];
            *(float4*)(pb + c * 16)     = s0;
            *(float4*)(pb + c * 16 + 4) = s1;
        }
    }
}

// ---------------- reduce kernel: s = sum_g part; squash; emit v ----------------
// MODE 1: vout = squash(s/3)   MODE 2: vout = squash(s) + vin   MODE 3: vout = squash(s)
template<int MODE>
__global__ __launch_bounds__(256, 4)
void caps_reduce(const float* __restrict__ part, const float* __restrict__ vin,
                 float* __restrict__ vout)
{
    const int t = blockIdx.x * 256 + threadIdx.x;   // 0 .. B*CD-1
    float s = 0.f;
#pragma unroll 7
    for (int g = 0; g < NCHUNK; ++g) s += part[(size_t)g * (BB * CD) + t];
    if (MODE == 1) s *= (1.0f / 3.0f);
    // squash over the 16 d of this (b,c): threads t..t+15 share (b,c)
    float q = s * s;
#pragma unroll
    for (int m = 1; m < 16; m <<= 1) q += __shfl_xor(q, m);
    float v = s * sqrtf(q) / (1.f + q);
    if (MODE == 2) v += __ldg(vin + t);
    vout[t] = v;
}

extern "C" void kernel_launch(void* const* d_in, const int* in_sizes, int n_in,
                              void* d_out, int out_size, void* d_ws, size_t ws_size,
                              hipStream_t stream) {
    (void)in_sizes; (void)n_in; (void)out_size;
    const float* x = (const float*)d_in[0];   // (B, N, 8) fp32
    const float* W = (const float*)d_in[1];   // (1, 3, N, 16, 8) fp32

    const size_t part_bytes = (size_t)NCHUNK * BB * CD * sizeof(float);  // 38,535,168
    float* part = (float*)d_ws;
    float* v1   = (float*)((char*)d_ws + part_bytes);
    float* w2   = v1 + BB * CD;
    float* out  = (float*)d_out;
    if (ws_size < part_bytes + 2 * BB * CD * sizeof(float)) return;

    const dim3 pg(NCHUNK * 64), pb(256);      // 64 b-groups of 32
    const dim3 rg((BB * CD) / 256), rb(256);

    hipLaunchKernelGGL(caps_pass<0>,   pg, pb, 0, stream, x, W, nullptr, part);
    hipLaunchKernelGGL(caps_reduce<1>, rg, rb, 0, stream, part, nullptr, v1);
    hipLaunchKernelGGL(caps_pass<1>,   pg, pb, 0, stream, x, W, v1, part);
    hipLaunchKernelGGL(caps_reduce<2>, rg, rb, 0, stream, part, v1, w2);
    hipLaunchKernelGGL(caps_pass<2>,   pg, pb, 0, stream, x, W, w2, part);
    hipLaunchKernelGGL(caps_reduce<3>, rg, rb, 0, stream, part, nullptr, out);
}

// Round 4
// 670.527 us; speedup vs baseline: 1.0973x; 1.0973x over previous
//
#include <hip/hip_runtime.h>

#define BB 2048
#define NN 1568
#define CD 48
#define NCHUNK 98          // n-chunks of 16; 98*16 = 1568

// ---------------- pass kernel: lane = batch, W loads are wave-uniform (scalar) ----------------
// block = 64 threads = 1 wave = 64 batches. Each thread computes ALL 48 cd for its batch.
// W addresses depend only on (blockIdx, loop counters) -> s_load into SGPRs, scalar cache.
// PASS 0: part[g][b][cd] = sum_n u[b,n,cd]
// PASS 1/2: part[g][b][cd] = sum_n softmax_c(vin . u) * u
// NOTE: no float4 casts of local arrays anywhere (round-3 spill lesson).
template<int PASS>
__global__ __launch_bounds__(64, 3)
void caps_pass(const float* __restrict__ x, const float* __restrict__ W,
               const float* __restrict__ vin, float* __restrict__ part)
{
    const int l  = threadIdx.x;          // batch lane
    const int bg = blockIdx.x & 31;      // 32 batch groups of 64
    const int g  = blockIdx.x >> 5;      // 98 n-chunks
    const int b  = bg * 64 + l;
    const int n0 = g * 16;

    float vv[CD];
    if (PASS > 0) {
#pragma unroll
        for (int j = 0; j < 12; ++j) {
            const float4 t = __ldg((const float4*)(vin + b * CD + j * 4));
            vv[j*4+0] = t.x; vv[j*4+1] = t.y; vv[j*4+2] = t.z; vv[j*4+3] = t.w;
        }
    }

    float acc[CD];
#pragma unroll
    for (int j = 0; j < CD; ++j) acc[j] = 0.f;

    for (int i = 0; i < 16; ++i) {
        const int n = n0 + i;
        const float4 x0 = __ldg((const float4*)(x + ((size_t)b * NN + n) * 8));
        const float4 x1 = __ldg((const float4*)(x + ((size_t)b * NN + n) * 8 + 4));

        float U[CD];
#pragma unroll
        for (int c = 0; c < 3; ++c) {
            const float* wr = W + ((size_t)(c * NN + n)) * 128;  // wave-uniform base
#pragma unroll
            for (int d = 0; d < 16; ++d) {
                // uniform address -> scalar load; W values become SGPR operands of v_fmac
                const float4 w0 = *(const float4*)(wr + d * 8);
                const float4 w1 = *(const float4*)(wr + d * 8 + 4);
                U[c*16+d] = w0.x*x0.x + w0.y*x0.y + w0.z*x0.z + w0.w*x0.w
                          + w1.x*x1.x + w1.y*x1.y + w1.z*x1.z + w1.w*x1.w;
            }
        }

        if (PASS == 0) {
#pragma unroll
            for (int j = 0; j < CD; ++j) acc[j] += U[j];
        } else {
            float l0 = 0.f, l1 = 0.f, l2 = 0.f;
#pragma unroll
            for (int d = 0; d < 16; ++d) {
                l0 += vv[d]      * U[d];
                l1 += vv[16 + d] * U[16 + d];
                l2 += vv[32 + d] * U[32 + d];
            }
            const float mx = fmaxf(l0, fmaxf(l1, l2));
            const float e0 = __expf(l0 - mx), e1 = __expf(l1 - mx), e2 = __expf(l2 - mx);
            const float inv = 1.f / (e0 + e1 + e2);
            const float c0 = e0 * inv, c1 = e1 * inv, c2 = e2 * inv;
#pragma unroll
            for (int d = 0; d < 16; ++d) {
                acc[d]      += c0 * U[d];
                acc[16 + d] += c1 * U[16 + d];
                acc[32 + d] += c2 * U[32 + d];
            }
        }
    }

    // store partials: part[g][b][cd], element-wise float4 construction (no array casts)
    float* pb = part + ((size_t)g * BB + b) * CD;
#pragma unroll
    for (int j = 0; j < 12; ++j) {
        float4 s;
        s.x = acc[j*4+0]; s.y = acc[j*4+1]; s.z = acc[j*4+2]; s.w = acc[j*4+3];
        *(float4*)(pb + j * 4) = s;
    }
}

// ---------------- reduce kernel: s = sum_g part; squash; emit v ----------------
// float2 per thread: elements (2t, 2t+1). Lanes t..t+7 cover the 16 d of one (b,c).
// MODE 1: vout = squash(s/3)   MODE 2: vout = squash(s) + vin   MODE 3: vout = squash(s)
template<int MODE>
__global__ __launch_bounds__(256, 4)
void caps_reduce(const float* __restrict__ part, const float* __restrict__ vin,
                 float* __restrict__ vout)
{
    const int t = blockIdx.x * 256 + threadIdx.x;   // 0 .. B*CD/2-1
    float s0 = 0.f, s1 = 0.f;
    float t0 = 0.f, t1 = 0.f;
#pragma unroll 7
    for (int g = 0; g < NCHUNK; g += 2) {
        const float2 a = *(const float2*)(part + (size_t)g * (BB * CD) + 2 * t);
        const float2 bq = *(const float2*)(part + (size_t)(g + 1) * (BB * CD) + 2 * t);
        s0 += a.x; s1 += a.y;
        t0 += bq.x; t1 += bq.y;
    }
    s0 += t0; s1 += t1;
    if (MODE == 1) { s0 *= (1.0f / 3.0f); s1 *= (1.0f / 3.0f); }
    // squash over 16 d shared by 8 consecutive lanes
    float q = s0 * s0 + s1 * s1;
#pragma unroll
    for (int m = 1; m < 8; m <<= 1) q += __shfl_xor(q, m);
    const float f = sqrtf(q) / (1.f + q);
    float v0 = s0 * f, v1 = s1 * f;
    if (MODE == 2) {
        const float2 w = *(const float2*)(vin + 2 * t);
        v0 += w.x; v1 += w.y;
    }
    float2 o; o.x = v0; o.y = v1;
    *(float2*)(vout + 2 * t) = o;
}

extern "C" void kernel_launch(void* const* d_in, const int* in_sizes, int n_in,
                              void* d_out, int out_size, void* d_ws, size_t ws_size,
                              hipStream_t stream) {
    (void)in_sizes; (void)n_in; (void)out_size;
    const float* x = (const float*)d_in[0];   // (B, N, 8) fp32
    const float* W = (const float*)d_in[1];   // (1, 3, N, 16, 8) fp32

    const size_t part_bytes = (size_t)NCHUNK * BB * CD * sizeof(float);  // 38,535,168
    float* part = (float*)d_ws;
    float* v1   = (float*)((char*)d_ws + part_bytes);
    float* w2   = v1 + BB * CD;
    float* out  = (float*)d_out;
    if (ws_size < part_bytes + 2 * BB * CD * sizeof(float)) return;

    const dim3 pg(NCHUNK * 32), pb(64);            // 3136 waves, lane = batch
    const dim3 rg((BB * CD / 2) / 256), rb(256);   // 192 blocks, float2/thread

    hipLaunchKernelGGL(caps_pass<0>,   pg, pb, 0, stream, x, W, nullptr, part);
    hipLaunchKernelGGL(caps_reduce<1>, rg, rb, 0, stream, part, nullptr, v1);
    hipLaunchKernelGGL(caps_pass<1>,   pg, pb, 0, stream, x, W, v1, part);
    hipLaunchKernelGGL(caps_reduce<2>, rg, rb, 0, stream, part, v1, w2);
    hipLaunchKernelGGL(caps_pass<2>,   pg, pb, 0, stream, x, W, w2, part);
    hipLaunchKernelGGL(caps_reduce<3>, rg, rb, 0, stream, part, nullptr, out);
}

// Round 5
// 435.513 us; speedup vs baseline: 1.6894x; 1.5396x over previous
//
#include <hip/hip_runtime.h>
#include <hip/hip_fp16.h>

#define BB 2048
#define NN 1568
#define CD 48

// ---- scalar-safe half2 pack/unpack (no local-array casts — round-3 spill lesson)
__device__ __forceinline__ unsigned packh2(float a, float b) {
    __half2 h = __floats2half2_rn(a, b);
    unsigned r; __builtin_memcpy(&r, &h, 4); return r;
}
__device__ __forceinline__ float2 uph2(unsigned v) {
    __half2 h; __builtin_memcpy(&h, &v, 4); return __half22float2(h);
}

// =================== K1: u[b][n][cd] fp16 ===================
// grid = 98 g * 64 bg; block 256 = bl32 x h2 x ns4. Block covers 32 b x 16 n.
// W tile staged in LDS (coalesced); x per-thread in registers; u stores per c:
// 16B at half-offset c*16 + h*8 -> per block each b gets contiguous 1536 B.
__global__ __launch_bounds__(256, 3)
void k1_u(const float* __restrict__ x, const float* __restrict__ W,
          __half* __restrict__ u)
{
    __shared__ float wlds[16 * 384];   // 24,576 B: [n-row][c*128 + d*8 + e]
    const int t  = threadIdx.x;
    const int bl = t & 31;
    const int h  = (t >> 5) & 1;
    const int ns = t >> 6;
    const int bg = blockIdx.x & 63;
    const int g  = blockIdx.x >> 6;
    const int b  = bg * 32 + bl;
    const int n0 = g * 16;

    // x for this thread's 4 n (independent of LDS staging; issues early)
    float xr[32];
#pragma unroll
    for (int i = 0; i < 4; ++i) {
        const float* xp = x + ((size_t)b * NN + n0 + ns * 4 + i) * 8;
        const float4 a = __ldg((const float4*)xp);
        const float4 c = __ldg((const float4*)(xp + 4));
        xr[i*8+0]=a.x; xr[i*8+1]=a.y; xr[i*8+2]=a.z; xr[i*8+3]=a.w;
        xr[i*8+4]=c.x; xr[i*8+5]=c.y; xr[i*8+6]=c.z; xr[i*8+7]=c.w;
    }

    // stage W[c, n0:n0+16, :, :] -> wlds, coalesced (6 float4/thread)
#pragma unroll
    for (int k = 0; k < 6; ++k) {
        const int q = t + k * 256;           // float4 index 0..1535
        const int c = q >> 9;
        const int j = (q >> 5) & 15;
        const int f = q & 31;
        const float4 v = *(const float4*)(W + (((size_t)(c * NN + n0 + j)) << 7) + (f << 2));
        *(float4*)(wlds + j * 384 + c * 128 + (f << 2)) = v;
    }
    __syncthreads();

#pragma unroll
    for (int i = 0; i < 4; ++i) {
        const int nr = ns * 4 + i;
        const int n  = n0 + nr;
        const float x0 = xr[i*8+0], x1 = xr[i*8+1], x2 = xr[i*8+2], x3 = xr[i*8+3];
        const float x4 = xr[i*8+4], x5 = xr[i*8+5], x6 = xr[i*8+6], x7 = xr[i*8+7];
        __half* dst = u + ((size_t)b * NN + n) * CD + h * 8;  // + c*16 per class

#pragma unroll
        for (int c = 0; c < 3; ++c) {
            const float* wc = wlds + nr * 384 + c * 128 + h * 64;  // 8 d-rows of 8 e
            uint4 pk;
#pragma unroll
            for (int pp = 0; pp < 4; ++pp) {   // dd = 2pp, 2pp+1
                const float4 w0 = *(const float4*)(wc + 16 * pp);
                const float4 w1 = *(const float4*)(wc + 16 * pp + 4);
                const float4 w2 = *(const float4*)(wc + 16 * pp + 8);
                const float4 w3 = *(const float4*)(wc + 16 * pp + 12);
                const float a0 = w0.x*x0 + w0.y*x1 + w0.z*x2 + w0.w*x3
                               + w1.x*x4 + w1.y*x5 + w1.z*x6 + w1.w*x7;
                const float a1 = w2.x*x0 + w2.y*x1 + w2.z*x2 + w2.w*x3
                               + w3.x*x4 + w3.y*x5 + w3.z*x6 + w3.w*x7;
                const unsigned pv = packh2(a0, a1);
                if (pp == 0) pk.x = pv; else if (pp == 1) pk.y = pv;
                else if (pp == 2) pk.z = pv; else pk.w = pv;
            }
            *(uint4*)(dst + c * 16) = pk;   // 16 B: cd = c*16 + h*8 .. +8
        }
    }
}

// =================== K2: full routing, one block per batch ===================
// block 256 = 4 waves; lane-adjacent n -> coalesced 64x96B u streams.
// sub-pass 0: s1 = sum u /3 -> v1; sub-pass 1: logits v1 -> s2 -> v2, w2=v1+v2;
// sub-pass 2: logits w2 -> s3 -> out = squash(s3).
__global__ __launch_bounds__(256, 3)
void k2_route(const __half* __restrict__ u, float* __restrict__ out)
{
    __shared__ float red[4][CD];
    __shared__ float vsh[CD];

    const int t = threadIdx.x;
    const int w = t >> 6;
    const int b = blockIdx.x;
    const __half* ub = u + (size_t)b * NN * CD;

    float acc[CD];

    // ---------- sub-pass 0: s1 ----------
#pragma unroll
    for (int i = 0; i < CD; ++i) acc[i] = 0.f;
    for (int n = t; n < NN; n += 256) {
        const uint4* p = (const uint4*)(ub + (size_t)n * CD);
        const uint4 r0 = p[0], r1 = p[1], r2 = p[2], r3 = p[3], r4 = p[4], r5 = p[5];
        const unsigned rr[24] = { r0.x,r0.y,r0.z,r0.w, r1.x,r1.y,r1.z,r1.w,
                                  r2.x,r2.y,r2.z,r2.w, r3.x,r3.y,r3.z,r3.w,
                                  r4.x,r4.y,r4.z,r4.w, r5.x,r5.y,r5.z,r5.w };
#pragma unroll
        for (int j = 0; j < 24; ++j) {
            const float2 f = uph2(rr[j]);
            acc[2*j] += f.x; acc[2*j+1] += f.y;
        }
    }
    // wave allreduce + cross-wave
#pragma unroll
    for (int i = 0; i < CD; ++i) {
        float v = acc[i];
        v += __shfl_xor(v, 1); v += __shfl_xor(v, 2); v += __shfl_xor(v, 4);
        v += __shfl_xor(v, 8); v += __shfl_xor(v, 16); v += __shfl_xor(v, 32);
        acc[i] = v;
    }
    if ((t & 63) == 0) { for (int i = 0; i < CD; ++i) red[w][i] = acc[i]; }
    __syncthreads();
    if (t < CD) {
        float s = (red[0][t] + red[1][t] + red[2][t] + red[3][t]) * (1.0f / 3.0f);
        float q = s * s;
        q += __shfl_xor(q, 1); q += __shfl_xor(q, 2); q += __shfl_xor(q, 4); q += __shfl_xor(q, 8);
        vsh[t] = s * sqrtf(q) / (1.f + q);    // v1
    }
    __syncthreads();

    // ---------- sub-passes 1,2 ----------
#pragma unroll 1
    for (int pass = 1; pass <= 2; ++pass) {
        float wv[CD];
#pragma unroll
        for (int i = 0; i < CD; ++i) wv[i] = vsh[i];
#pragma unroll
        for (int i = 0; i < CD; ++i) acc[i] = 0.f;

        for (int n = t; n < NN; n += 256) {
            const uint4* p = (const uint4*)(ub + (size_t)n * CD);
            const uint4 r0 = p[0], r1 = p[1], r2 = p[2], r3 = p[3], r4 = p[4], r5 = p[5];
            const unsigned rr[24] = { r0.x,r0.y,r0.z,r0.w, r1.x,r1.y,r1.z,r1.w,
                                      r2.x,r2.y,r2.z,r2.w, r3.x,r3.y,r3.z,r3.w,
                                      r4.x,r4.y,r4.z,r4.w, r5.x,r5.y,r5.z,r5.w };
            float l0 = 0.f, l1 = 0.f, l2 = 0.f;
#pragma unroll
            for (int j = 0; j < 8; ++j) {
                const float2 f0 = uph2(rr[j]);
                const float2 f1 = uph2(rr[8 + j]);
                const float2 f2 = uph2(rr[16 + j]);
                l0 += wv[2*j]      * f0.x + wv[2*j+1]      * f0.y;
                l1 += wv[16+2*j]   * f1.x + wv[16+2*j+1]   * f1.y;
                l2 += wv[32+2*j]   * f2.x + wv[32+2*j+1]   * f2.y;
            }
            // |logit| < ~0.1 — no max-shift needed
            const float e0 = __expf(l0), e1 = __expf(l1), e2 = __expf(l2);
            const float inv = 1.f / (e0 + e1 + e2);
            const float c0 = e0 * inv, c1 = e1 * inv, c2 = e2 * inv;
#pragma unroll
            for (int j = 0; j < 8; ++j) {
                const float2 f0 = uph2(rr[j]);
                const float2 f1 = uph2(rr[8 + j]);
                const float2 f2 = uph2(rr[16 + j]);
                acc[2*j]      += c0 * f0.x;  acc[2*j+1]      += c0 * f0.y;
                acc[16+2*j]   += c1 * f1.x;  acc[16+2*j+1]   += c1 * f1.y;
                acc[32+2*j]   += c2 * f2.x;  acc[32+2*j+1]   += c2 * f2.y;
            }
        }
#pragma unroll
        for (int i = 0; i < CD; ++i) {
            float v = acc[i];
            v += __shfl_xor(v, 1); v += __shfl_xor(v, 2); v += __shfl_xor(v, 4);
            v += __shfl_xor(v, 8); v += __shfl_xor(v, 16); v += __shfl_xor(v, 32);
            acc[i] = v;
        }
        if ((t & 63) == 0) { for (int i = 0; i < CD; ++i) red[w][i] = acc[i]; }
        __syncthreads();
        if (t < CD) {
            const float s = red[0][t] + red[1][t] + red[2][t] + red[3][t];
            float q = s * s;
            q += __shfl_xor(q, 1); q += __shfl_xor(q, 2); q += __shfl_xor(q, 4); q += __shfl_xor(q, 8);
            const float v = s * sqrtf(q) / (1.f + q);
            if (pass == 1) vsh[t] = wv[t] + v;        // w2 = v1 + v2
            else           out[b * CD + t] = v;       // final
        }
        __syncthreads();
    }
}

extern "C" void kernel_launch(void* const* d_in, const int* in_sizes, int n_in,
                              void* d_out, int out_size, void* d_ws, size_t ws_size,
                              hipStream_t stream) {
    (void)in_sizes; (void)n_in; (void)out_size;
    const float* x = (const float*)d_in[0];   // (B, N, 8) fp32
    const float* W = (const float*)d_in[1];   // (1, 3, N, 16, 8) fp32
    const size_t u_bytes = (size_t)BB * NN * CD * sizeof(__half);  // 308,281,344
    if (ws_size < u_bytes) return;
    __half* u = (__half*)d_ws;

    hipLaunchKernelGGL(k1_u,     dim3(98 * 64), dim3(256), 0, stream, x, W, u);
    hipLaunchKernelGGL(k2_route, dim3(BB),      dim3(256), 0, stream, u, (float*)d_out);
}